// Round 1
// baseline (4284.059 us; speedup 1.0000x reference)
//
#include <hip/hip_runtime.h>
#include <stdint.h>
#include <math.h>

#define B_ 16
#define T_ 2048
#define D_ 256
#define N_ (B_*T_*D_)   // 8388608

// ---------------- JAX threefry2x32 (partitionable layout) ----------------
__device__ __forceinline__ uint32_t rotl32(uint32_t v, int r) {
  return (v << r) | (v >> (32 - r));
}

__device__ __forceinline__ void threefry2x32(uint32_t k0, uint32_t k1,
                                             uint32_t x0, uint32_t x1,
                                             uint32_t& o0, uint32_t& o1) {
  uint32_t ks2 = k0 ^ k1 ^ 0x1BD11BDAu;
#define TF_ROUND(r) { x0 += x1; x1 = rotl32(x1, r); x1 ^= x0; }
  x0 += k0; x1 += k1;
  TF_ROUND(13) TF_ROUND(15) TF_ROUND(26) TF_ROUND(6)
  x0 += k1; x1 += ks2 + 1u;
  TF_ROUND(17) TF_ROUND(29) TF_ROUND(16) TF_ROUND(24)
  x0 += ks2; x1 += k0 + 2u;
  TF_ROUND(13) TF_ROUND(15) TF_ROUND(26) TF_ROUND(6)
  x0 += k0; x1 += k1 + 3u;
  TF_ROUND(17) TF_ROUND(29) TF_ROUND(16) TF_ROUND(24)
  x0 += k1; x1 += ks2 + 4u;
  TF_ROUND(13) TF_ROUND(15) TF_ROUND(26) TF_ROUND(6)
  x0 += ks2; x1 += k0 + 5u;
#undef TF_ROUND
  o0 = x0; o1 = x1;
}

// XLA ErfInv f32 polynomial (Giles)
__device__ __forceinline__ float erfinv_xla(float x) {
  float w = -log1pf(-x * x);
  float p;
  if (w < 5.0f) {
    w -= 2.5f;
    p = 2.81022636e-08f;
    p = fmaf(p, w, 3.43273939e-07f);
    p = fmaf(p, w, -3.5233877e-06f);
    p = fmaf(p, w, -4.39150654e-06f);
    p = fmaf(p, w, 0.00021858087f);
    p = fmaf(p, w, -0.00125372503f);
    p = fmaf(p, w, -0.00417768164f);
    p = fmaf(p, w, 0.246640727f);
    p = fmaf(p, w, 1.50140941f);
  } else {
    w = sqrtf(w) - 3.0f;
    p = -0.000200214257f;
    p = fmaf(p, w, 0.000100950558f);
    p = fmaf(p, w, 0.00134934322f);
    p = fmaf(p, w, -0.00367342844f);
    p = fmaf(p, w, 0.00573950773f);
    p = fmaf(p, w, -0.0076224613f);
    p = fmaf(p, w, 0.00943887047f);
    p = fmaf(p, w, 1.00167406f);
    p = fmaf(p, w, 2.83297682f);
  }
  return p * x;
}

// jax.random.normal element n (flat row-major index), key=(0, seed)
__device__ __forceinline__ float jax_normal_elem(uint32_t key, uint32_t n) {
  uint32_t o0, o1;
  threefry2x32(0u, key, 0u, n, o0, o1);
  uint32_t bits = o0 ^ o1;                     // partitionable 32-bit output
  float f = __uint_as_float((bits >> 9) | 0x3f800000u) - 1.0f;  // [0,1)
  const float lo = -0.99999994f;               // nextafter(-1,0)
  float u = fmaxf(lo, fmaf(f, 2.0f, lo));      // (maxval-minval) rounds to 2.0f
  return 1.41421356f * erfinv_xla(u);          // sqrt(2) in f32
}

// ---------------- mean over T ----------------
__global__ __launch_bounds__(1024) void mean_k(const float* __restrict__ A,
    const float* __restrict__ Vv, float* __restrict__ muA, float* __restrict__ muV) {
  const float* X = blockIdx.y ? Vv : A;
  float* mu = blockIdx.y ? muV : muA;
  int b = blockIdx.x;
  int d = threadIdx.x & 255;
  int part = threadIdx.x >> 8;   // 0..3
  __shared__ float partial[4][256];
  const float* p = X + ((size_t)b*T_ + (size_t)part*(T_/4))*D_ + d;
  float s = 0.f;
  for (int t = 0; t < T_/4; ++t) s += p[(size_t)t * D_];
  partial[part][d] = s;
  __syncthreads();
  if (part == 0)
    mu[b*D_ + d] = (partial[0][d] + partial[1][d] + partial[2][d] + partial[3][d]) * (1.0f/(float)T_);
}

// ---------------- Sigma = Xc^T Xc / (T-1), lower tiles only, +jitter on diag ----------------
__global__ __launch_bounds__(256) void sigma_k(const float* __restrict__ A,
    const float* __restrict__ Vv, const float* __restrict__ muA,
    const float* __restrict__ muV, float* __restrict__ SA, float* __restrict__ SV) {
  const float* X  = blockIdx.z ? Vv  : A;
  const float* mu = blockIdx.z ? muV : muA;
  float* Sg       = blockIdx.z ? SV  : SA;
  const int TIa[10] = {0,1,1,2,2,2,3,3,3,3};
  const int TJa[10] = {0,0,1,0,1,2,0,1,2,3};
  int b = blockIdx.y;
  int I0 = TIa[blockIdx.x]*64, J0 = TJa[blockIdx.x]*64;
  __shared__ float xi[16][64];
  __shared__ float xj[16][64];
  int tid = threadIdx.x;
  int r = tid >> 4, c4 = (tid & 15) * 4;
  float4 mI = *(const float4*)(mu + b*D_ + I0 + c4);
  float4 mJ = *(const float4*)(mu + b*D_ + J0 + c4);
  float acc[4][4] = {};
  int i4 = (tid >> 4) * 4, j4 = (tid & 15) * 4;
  for (int t0 = 0; t0 < T_; t0 += 16) {
    __syncthreads();
    const float* px = X + ((size_t)b*T_ + t0 + r) * D_;
    float4 fa = *(const float4*)(px + I0 + c4);
    xi[r][c4+0] = fa.x - mI.x; xi[r][c4+1] = fa.y - mI.y;
    xi[r][c4+2] = fa.z - mI.z; xi[r][c4+3] = fa.w - mI.w;
    float4 fb = *(const float4*)(px + J0 + c4);
    xj[r][c4+0] = fb.x - mJ.x; xj[r][c4+1] = fb.y - mJ.y;
    xj[r][c4+2] = fb.z - mJ.z; xj[r][c4+3] = fb.w - mJ.w;
    __syncthreads();
    #pragma unroll
    for (int t = 0; t < 16; ++t) {
      float4 qa = *(const float4*)&xi[t][i4];
      float4 qb = *(const float4*)&xj[t][j4];
      acc[0][0] = fmaf(qa.x, qb.x, acc[0][0]); acc[0][1] = fmaf(qa.x, qb.y, acc[0][1]);
      acc[0][2] = fmaf(qa.x, qb.z, acc[0][2]); acc[0][3] = fmaf(qa.x, qb.w, acc[0][3]);
      acc[1][0] = fmaf(qa.y, qb.x, acc[1][0]); acc[1][1] = fmaf(qa.y, qb.y, acc[1][1]);
      acc[1][2] = fmaf(qa.y, qb.z, acc[1][2]); acc[1][3] = fmaf(qa.y, qb.w, acc[1][3]);
      acc[2][0] = fmaf(qa.z, qb.x, acc[2][0]); acc[2][1] = fmaf(qa.z, qb.y, acc[2][1]);
      acc[2][2] = fmaf(qa.z, qb.z, acc[2][2]); acc[2][3] = fmaf(qa.z, qb.w, acc[2][3]);
      acc[3][0] = fmaf(qa.w, qb.x, acc[3][0]); acc[3][1] = fmaf(qa.w, qb.y, acc[3][1]);
      acc[3][2] = fmaf(qa.w, qb.z, acc[3][2]); acc[3][3] = fmaf(qa.w, qb.w, acc[3][3]);
    }
  }
  const float inv = 1.0f / (float)(T_ - 1);
  float* out = Sg + (size_t)b*D_*D_;
  #pragma unroll
  for (int ii = 0; ii < 4; ++ii)
    #pragma unroll
    for (int jj = 0; jj < 4; ++jj) {
      int row = I0 + i4 + ii, col = J0 + j4 + jj;
      float v = acc[ii][jj] * inv;
      if (row == col) v += 1e-6f;
      out[(size_t)row*D_ + col] = v;
    }
}

// ---------------- left-looking Cholesky, one block per (batch, modality) ----------------
__global__ __launch_bounds__(256) void chol_k(float* __restrict__ SA, float* __restrict__ SV) {
  float* M = (blockIdx.y ? SV : SA) + (size_t)blockIdx.x * D_ * D_;
  __shared__ float rowj[256];
  __shared__ float dshare;
  int i = threadIdx.x;
  float* rowi = M + (size_t)i * D_;
  for (int j = 0; j < D_; ++j) {
    __syncthreads();
    if (i < j) rowj[i] = M[(size_t)j*D_ + i];
    __syncthreads();
    float dot = 0.f;
    if (i >= j) {
      float d0 = 0.f, d1 = 0.f, d2 = 0.f, d3 = 0.f;
      int j16 = j & ~15;
      for (int k = 0; k < j16; k += 16) {
        float4 a0 = *(const float4*)(rowi + k);
        float4 a1 = *(const float4*)(rowi + k + 4);
        float4 a2 = *(const float4*)(rowi + k + 8);
        float4 a3 = *(const float4*)(rowi + k + 12);
        d0 += a0.x*rowj[k]    + a0.y*rowj[k+1]  + a0.z*rowj[k+2]  + a0.w*rowj[k+3];
        d1 += a1.x*rowj[k+4]  + a1.y*rowj[k+5]  + a1.z*rowj[k+6]  + a1.w*rowj[k+7];
        d2 += a2.x*rowj[k+8]  + a2.y*rowj[k+9]  + a2.z*rowj[k+10] + a2.w*rowj[k+11];
        d3 += a3.x*rowj[k+12] + a3.y*rowj[k+13] + a3.z*rowj[k+14] + a3.w*rowj[k+15];
      }
      for (int k = j16; k < j; ++k) d0 += rowi[k]*rowj[k];
      dot = (d0 + d1) + (d2 + d3);
    }
    if (i == j) dshare = sqrtf(rowi[j] - dot);
    __syncthreads();
    if (i > j)       rowi[j] = (rowi[j] - dot) / dshare;
    else if (i == j) rowi[j] = dshare;
  }
  __syncthreads();
  for (int k = i + 1; k < D_; ++k) rowi[k] = 0.f;   // zero upper triangle
}

// ---------------- K = mu + eps @ L^T with on-the-fly eps generation ----------------
__global__ __launch_bounds__(256) void kgen_k(const float* __restrict__ L,
    const float* __restrict__ mu, float* __restrict__ Kout, uint32_t key) {
  __shared__ float eps[64][16];
  int b = blockIdx.y;
  int t0 = blockIdx.x * 64;
  int e = threadIdx.x;
  const float* Lr = L + (size_t)b*D_*D_ + (size_t)e*D_;
  float acc[64];
  #pragma unroll
  for (int t = 0; t < 64; ++t) acc[t] = 0.f;
  int gt = threadIdx.x >> 2;
  int gd = (threadIdx.x & 3) * 4;
  for (int d0 = 0; d0 < D_; d0 += 16) {
    __syncthreads();
    uint32_t nbase = ((uint32_t)(b*T_ + t0 + gt)) * (uint32_t)D_ + (uint32_t)(d0 + gd);
    #pragma unroll
    for (int q = 0; q < 4; ++q) eps[gt][gd+q] = jax_normal_elem(key, nbase + q);
    __syncthreads();
    float lreg[16];
    #pragma unroll
    for (int q = 0; q < 16; q += 4) {
      float4 f = *(const float4*)(Lr + d0 + q);
      lreg[q] = f.x; lreg[q+1] = f.y; lreg[q+2] = f.z; lreg[q+3] = f.w;
    }
    #pragma unroll 8
    for (int t = 0; t < 64; ++t) {
      float s = acc[t];
      #pragma unroll
      for (int dd = 0; dd < 16; ++dd) s = fmaf(eps[t][dd], lreg[dd], s);
      acc[t] = s;
    }
  }
  float m = mu[b*D_ + e];
  for (int t = 0; t < 64; ++t)
    Kout[((size_t)b*T_ + t0 + t)*D_ + e] = acc[t] + m;
}

// ---------------- flash attention: O = softmax(Q K^T / 16) V ----------------
#define BQ 32
#define BS 64
#define SCALE_ 0.0625f

__global__ __launch_bounds__(256) void attn_k(const float* __restrict__ Qg,
    const float* __restrict__ Kg, const float* __restrict__ Vg,
    float* __restrict__ Og) {
  __shared__ float Qt[256][36];        // Q transposed [d][q]
  __shared__ float KV[64*68];          // Kc [dd][s] stride 68 / Vc [s][d] stride 260
  __shared__ float Pt[64][36];         // scores/probs transposed [s][q]
  __shared__ float rowm[BQ], rowl[BQ], rowa[BQ];
  int tid = threadIdx.x;
  int b = blockIdx.y;
  int t0 = blockIdx.x * BQ;

  #pragma unroll
  for (int it = 0; it < 8; ++it) {
    int flat = it*1024 + tid*4;
    int q = flat >> 8;
    int d = flat & 255;
    float4 f = *(const float4*)(Qg + ((size_t)b*T_ + t0 + q)*D_ + d);
    Qt[d+0][q] = f.x; Qt[d+1][q] = f.y; Qt[d+2][q] = f.z; Qt[d+3][q] = f.w;
  }
  if (tid < BQ) { rowm[tid] = -INFINITY; rowl[tid] = 0.f; rowa[tid] = 0.f; }

  int q4 = (tid >> 5) * 4;
  int sg = tid & 31;
  int dg = tid & 31;
  float acc[4][8];
  #pragma unroll
  for (int i = 0; i < 4; ++i)
    #pragma unroll
    for (int k = 0; k < 8; ++k) acc[i][k] = 0.f;

  for (int s0 = 0; s0 < T_; s0 += BS) {
    // ---- S = Q K^T (d-chunked) ----
    float sc[4][2] = {{0,0},{0,0},{0,0},{0,0}};
    for (int d0 = 0; d0 < D_; d0 += 64) {
      __syncthreads();
      #pragma unroll
      for (int it = 0; it < 4; ++it) {
        int flat = it*1024 + tid*4;
        int s = flat >> 6;
        int dd = flat & 63;
        float4 f = *(const float4*)(Kg + ((size_t)b*T_ + s0 + s)*D_ + d0 + dd);
        KV[(dd+0)*68 + s] = f.x; KV[(dd+1)*68 + s] = f.y;
        KV[(dd+2)*68 + s] = f.z; KV[(dd+3)*68 + s] = f.w;
      }
      __syncthreads();
      #pragma unroll 8
      for (int dd = 0; dd < 64; ++dd) {
        float4 qv = *(const float4*)&Qt[d0+dd][q4];
        float2 kv = *(const float2*)&KV[dd*68 + sg*2];
        sc[0][0] = fmaf(qv.x, kv.x, sc[0][0]); sc[0][1] = fmaf(qv.x, kv.y, sc[0][1]);
        sc[1][0] = fmaf(qv.y, kv.x, sc[1][0]); sc[1][1] = fmaf(qv.y, kv.y, sc[1][1]);
        sc[2][0] = fmaf(qv.z, kv.x, sc[2][0]); sc[2][1] = fmaf(qv.z, kv.y, sc[2][1]);
        sc[3][0] = fmaf(qv.w, kv.x, sc[3][0]); sc[3][1] = fmaf(qv.w, kv.y, sc[3][1]);
      }
    }
    #pragma unroll
    for (int qi = 0; qi < 4; ++qi) {
      Pt[sg*2+0][q4+qi] = sc[qi][0] * SCALE_;
      Pt[sg*2+1][q4+qi] = sc[qi][1] * SCALE_;
    }
    __syncthreads();
    // ---- online softmax: 8 threads per query row ----
    {
      int rq = tid >> 3;
      int sub = tid & 7;
      float mloc = -INFINITY;
      #pragma unroll
      for (int s = sub; s < BS; s += 8) mloc = fmaxf(mloc, Pt[s][rq]);
      mloc = fmaxf(mloc, __shfl_down(mloc, 4, 8));
      mloc = fmaxf(mloc, __shfl_down(mloc, 2, 8));
      mloc = fmaxf(mloc, __shfl_down(mloc, 1, 8));
      mloc = __shfl(mloc, 0, 8);
      float mold = rowm[rq];
      float mnew = fmaxf(mold, mloc);
      float ls = 0.f;
      #pragma unroll
      for (int s = sub; s < BS; s += 8) {
        float p = expf(Pt[s][rq] - mnew);
        Pt[s][rq] = p;
        ls += p;
      }
      ls += __shfl_down(ls, 4, 8);
      ls += __shfl_down(ls, 2, 8);
      ls += __shfl_down(ls, 1, 8);
      if (sub == 0) {
        float alpha = expf(mold - mnew);
        rowa[rq] = alpha;
        rowl[rq] = rowl[rq] * alpha + ls;
        rowm[rq] = mnew;
      }
    }
    __syncthreads();
    {
      float av0 = rowa[q4+0], av1 = rowa[q4+1], av2 = rowa[q4+2], av3 = rowa[q4+3];
      #pragma unroll
      for (int k = 0; k < 8; ++k) {
        acc[0][k] *= av0; acc[1][k] *= av1; acc[2][k] *= av2; acc[3][k] *= av3;
      }
    }
    // ---- O += P V (s-subtiled) ----
    for (int ss = 0; ss < BS; ss += 16) {
      __syncthreads();
      #pragma unroll
      for (int it = 0; it < 4; ++it) {
        int flat = it*1024 + tid*4;
        int s = flat >> 8;
        int d = flat & 255;
        float4 f = *(const float4*)(Vg + ((size_t)b*T_ + s0 + ss + s)*D_ + d);
        *(float4*)&KV[s*260 + d] = f;
      }
      __syncthreads();
      #pragma unroll 4
      for (int s = 0; s < 16; ++s) {
        float4 pv = *(const float4*)&Pt[ss+s][q4];
        const float* vrow = &KV[s*260];
        float4 v0 = *(const float4*)&vrow[dg*4];
        float4 v1 = *(const float4*)&vrow[128 + dg*4];
        acc[0][0]=fmaf(pv.x,v0.x,acc[0][0]); acc[0][1]=fmaf(pv.x,v0.y,acc[0][1]);
        acc[0][2]=fmaf(pv.x,v0.z,acc[0][2]); acc[0][3]=fmaf(pv.x,v0.w,acc[0][3]);
        acc[0][4]=fmaf(pv.x,v1.x,acc[0][4]); acc[0][5]=fmaf(pv.x,v1.y,acc[0][5]);
        acc[0][6]=fmaf(pv.x,v1.z,acc[0][6]); acc[0][7]=fmaf(pv.x,v1.w,acc[0][7]);
        acc[1][0]=fmaf(pv.y,v0.x,acc[1][0]); acc[1][1]=fmaf(pv.y,v0.y,acc[1][1]);
        acc[1][2]=fmaf(pv.y,v0.z,acc[1][2]); acc[1][3]=fmaf(pv.y,v0.w,acc[1][3]);
        acc[1][4]=fmaf(pv.y,v1.x,acc[1][4]); acc[1][5]=fmaf(pv.y,v1.y,acc[1][5]);
        acc[1][6]=fmaf(pv.y,v1.z,acc[1][6]); acc[1][7]=fmaf(pv.y,v1.w,acc[1][7]);
        acc[2][0]=fmaf(pv.z,v0.x,acc[2][0]); acc[2][1]=fmaf(pv.z,v0.y,acc[2][1]);
        acc[2][2]=fmaf(pv.z,v0.z,acc[2][2]); acc[2][3]=fmaf(pv.z,v0.w,acc[2][3]);
        acc[2][4]=fmaf(pv.z,v1.x,acc[2][4]); acc[2][5]=fmaf(pv.z,v1.y,acc[2][5]);
        acc[2][6]=fmaf(pv.z,v1.z,acc[2][6]); acc[2][7]=fmaf(pv.z,v1.w,acc[2][7]);
        acc[3][0]=fmaf(pv.w,v0.x,acc[3][0]); acc[3][1]=fmaf(pv.w,v0.y,acc[3][1]);
        acc[3][2]=fmaf(pv.w,v0.z,acc[3][2]); acc[3][3]=fmaf(pv.w,v0.w,acc[3][3]);
        acc[3][4]=fmaf(pv.w,v1.x,acc[3][4]); acc[3][5]=fmaf(pv.w,v1.y,acc[3][5]);
        acc[3][6]=fmaf(pv.w,v1.z,acc[3][6]); acc[3][7]=fmaf(pv.w,v1.w,acc[3][7]);
      }
    }
  }
  float inv[4];
  #pragma unroll
  for (int qi = 0; qi < 4; ++qi) inv[qi] = 1.0f / rowl[q4+qi];
  #pragma unroll
  for (int qi = 0; qi < 4; ++qi) {
    float* orow = Og + ((size_t)b*T_ + t0 + q4 + qi)*D_;
    float4 o0 = make_float4(acc[qi][0]*inv[qi], acc[qi][1]*inv[qi],
                            acc[qi][2]*inv[qi], acc[qi][3]*inv[qi]);
    float4 o1 = make_float4(acc[qi][4]*inv[qi], acc[qi][5]*inv[qi],
                            acc[qi][6]*inv[qi], acc[qi][7]*inv[qi]);
    *(float4*)(orow + dg*4) = o0;
    *(float4*)(orow + 128 + dg*4) = o1;
  }
}

// ---------------- gates + cosine combine (one wave per (b,t) row) ----------------
__global__ __launch_bounds__(256) void comb_k(const float* __restrict__ A,
    const float* __restrict__ Vv, const float* __restrict__ att1,
    const float* __restrict__ att2, const float* __restrict__ WA,
    const float* __restrict__ WV, const float* __restrict__ bA,
    const float* __restrict__ bV, float* __restrict__ out) {
  int wv = threadIdx.x >> 6;
  int lane = threadIdx.x & 63;
  size_t row = (size_t)blockIdx.x * 4 + wv;
  size_t base = row * D_;
  int d = lane * 4;
  float4 a  = *(const float4*)(A + base + d);
  float4 v  = *(const float4*)(Vv + base + d);
  float4 x  = *(const float4*)(att1 + base + d);
  float4 y  = *(const float4*)(att2 + base + d);
  float4 w1 = *(const float4*)(WA + d);
  float4 w2 = *(const float4*)(WA + 256 + d);
  float4 w3 = *(const float4*)(WV + d);
  float4 w4 = *(const float4*)(WV + 256 + d);
  float sga = a.x*w1.x + a.y*w1.y + a.z*w1.z + a.w*w1.w
            + x.x*w2.x + x.y*w2.y + x.z*w2.z + x.w*w2.w;
  float sgv = v.x*w3.x + v.y*w3.y + v.z*w3.z + v.w*w3.w
            + y.x*w4.x + y.y*w4.y + y.z*w4.z + y.w*w4.w;
  float sav = a.x*v.x + a.y*v.y + a.z*v.z + a.w*v.w;
  float saa = a.x*a.x + a.y*a.y + a.z*a.z + a.w*a.w;
  float svv = v.x*v.x + v.y*v.y + v.z*v.z + v.w*v.w;
  #pragma unroll
  for (int m = 32; m; m >>= 1) {
    sga += __shfl_xor(sga, m);
    sgv += __shfl_xor(sgv, m);
    sav += __shfl_xor(sav, m);
    saa += __shfl_xor(saa, m);
    svv += __shfl_xor(svv, m);
  }
  float gA = 1.0f / (1.0f + expf(-(sga + bA[0])));
  float gV = 1.0f / (1.0f + expf(-(sgv + bV[0])));
  float cs = sav / fmaxf(sqrtf(saa) * sqrtf(svv), 1e-8f);
  float al = 1.0f / (1.0f + expf(-cs));
  float be = 1.0f - al;
  float4 o;
  o.x = al * (gA*a.x + (1.0f-gA)*x.x) + be * (gV*v.x + (1.0f-gV)*y.x);
  o.y = al * (gA*a.y + (1.0f-gA)*x.y) + be * (gV*v.y + (1.0f-gV)*y.y);
  o.z = al * (gA*a.z + (1.0f-gA)*x.z) + be * (gV*v.z + (1.0f-gV)*y.z);
  o.w = al * (gA*a.w + (1.0f-gA)*x.w) + be * (gV*v.w + (1.0f-gV)*y.w);
  *(float4*)(out + base + d) = o;
}

extern "C" void kernel_launch(void* const* d_in, const int* in_sizes, int n_in,
                              void* d_out, int out_size, void* d_ws, size_t ws_size,
                              hipStream_t stream) {
  (void)in_sizes; (void)n_in; (void)out_size; (void)ws_size;
  const float* A  = (const float*)d_in[0];
  const float* V  = (const float*)d_in[1];
  const float* WA = (const float*)d_in[2];
  const float* WV = (const float*)d_in[3];
  const float* bA = (const float*)d_in[4];
  const float* bV = (const float*)d_in[5];
  float* ws  = (float*)d_ws;
  float* muA = ws;                                  // 4096
  float* muV = muA + 4096;                          // 4096
  float* LA  = muV + 4096;                          // 16*256*256
  float* LV  = LA + (size_t)B_*D_*D_;               // 16*256*256
  float* Kb  = LV + (size_t)B_*D_*D_;               // N_ (K_v then reused for K_a)
  float* at1 = Kb + (size_t)N_;                     // N_ att_av
  float* at2 = at1 + (size_t)N_;                    // N_ att_va
  // total ws: 27,271,168 floats = ~104 MB

  mean_k<<<dim3(16,2), dim3(1024), 0, stream>>>(A, V, muA, muV);
  sigma_k<<<dim3(10,16,2), dim3(256), 0, stream>>>(A, V, muA, muV, LA, LV);
  chol_k<<<dim3(16,2), dim3(256), 0, stream>>>(LA, LV);
  // K_v = resample(V, key 42): audio queries attend to it, values = V
  kgen_k<<<dim3(32,16), dim3(256), 0, stream>>>(LV, muV, Kb, 42u);
  attn_k<<<dim3(64,16), dim3(256), 0, stream>>>(A, Kb, V, at1);
  // K_a = resample(A, key 43): visual queries attend to it, values = A
  kgen_k<<<dim3(32,16), dim3(256), 0, stream>>>(LA, muA, Kb, 43u);
  attn_k<<<dim3(64,16), dim3(256), 0, stream>>>(V, Kb, A, at2);
  comb_k<<<dim3(8192), dim3(256), 0, stream>>>(A, V, at1, at2, WA, WV, bA, bV, (float*)d_out);
}

// Round 2
// 1996.591 us; speedup vs baseline: 2.1457x; 2.1457x over previous
//
#include <hip/hip_runtime.h>
#include <stdint.h>
#include <math.h>

#define B_ 16
#define T_ 2048
#define D_ 256
#define N_ (B_*T_*D_)   // 8388608

typedef __attribute__((ext_vector_type(8)))  __bf16 bf16x8;
typedef __attribute__((ext_vector_type(4)))  __bf16 bf16x4;
typedef __attribute__((ext_vector_type(2)))  __bf16 bf16x2;
typedef __attribute__((ext_vector_type(16))) float  float16;

// ---------------- JAX threefry2x32 (partitionable layout) ----------------
__device__ __forceinline__ uint32_t rotl32(uint32_t v, int r) {
  return (v << r) | (v >> (32 - r));
}

__device__ __forceinline__ void threefry2x32(uint32_t k0, uint32_t k1,
                                             uint32_t x0, uint32_t x1,
                                             uint32_t& o0, uint32_t& o1) {
  uint32_t ks2 = k0 ^ k1 ^ 0x1BD11BDAu;
#define TF_ROUND(r) { x0 += x1; x1 = rotl32(x1, r); x1 ^= x0; }
  x0 += k0; x1 += k1;
  TF_ROUND(13) TF_ROUND(15) TF_ROUND(26) TF_ROUND(6)
  x0 += k1; x1 += ks2 + 1u;
  TF_ROUND(17) TF_ROUND(29) TF_ROUND(16) TF_ROUND(24)
  x0 += ks2; x1 += k0 + 2u;
  TF_ROUND(13) TF_ROUND(15) TF_ROUND(26) TF_ROUND(6)
  x0 += k0; x1 += k1 + 3u;
  TF_ROUND(17) TF_ROUND(29) TF_ROUND(16) TF_ROUND(24)
  x0 += k1; x1 += ks2 + 4u;
  TF_ROUND(13) TF_ROUND(15) TF_ROUND(26) TF_ROUND(6)
  x0 += ks2; x1 += k0 + 5u;
#undef TF_ROUND
  o0 = x0; o1 = x1;
}

// XLA ErfInv f32 polynomial (Giles)
__device__ __forceinline__ float erfinv_xla(float x) {
  float w = -log1pf(-x * x);
  float p;
  if (w < 5.0f) {
    w -= 2.5f;
    p = 2.81022636e-08f;
    p = fmaf(p, w, 3.43273939e-07f);
    p = fmaf(p, w, -3.5233877e-06f);
    p = fmaf(p, w, -4.39150654e-06f);
    p = fmaf(p, w, 0.00021858087f);
    p = fmaf(p, w, -0.00125372503f);
    p = fmaf(p, w, -0.00417768164f);
    p = fmaf(p, w, 0.246640727f);
    p = fmaf(p, w, 1.50140941f);
  } else {
    w = sqrtf(w) - 3.0f;
    p = -0.000200214257f;
    p = fmaf(p, w, 0.000100950558f);
    p = fmaf(p, w, 0.00134934322f);
    p = fmaf(p, w, -0.00367342844f);
    p = fmaf(p, w, 0.00573950773f);
    p = fmaf(p, w, -0.0076224613f);
    p = fmaf(p, w, 0.00943887047f);
    p = fmaf(p, w, 1.00167406f);
    p = fmaf(p, w, 2.83297682f);
  }
  return p * x;
}

// jax.random.normal element n (flat row-major index), key=(0, seed)
__device__ __forceinline__ float jax_normal_elem(uint32_t key, uint32_t n) {
  uint32_t o0, o1;
  threefry2x32(0u, key, 0u, n, o0, o1);
  uint32_t bits = o0 ^ o1;                     // partitionable 32-bit output
  float f = __uint_as_float((bits >> 9) | 0x3f800000u) - 1.0f;  // [0,1)
  const float lo = -0.99999994f;               // nextafter(-1,0)
  float u = fmaxf(lo, fmaf(f, 2.0f, lo));      // (maxval-minval) rounds to 2.0f
  return 1.41421356f * erfinv_xla(u);          // sqrt(2) in f32
}

// ---------------- mean over T ----------------
__global__ __launch_bounds__(1024) void mean_k(const float* __restrict__ A,
    const float* __restrict__ Vv, float* __restrict__ muA, float* __restrict__ muV) {
  const float* X = blockIdx.y ? Vv : A;
  float* mu = blockIdx.y ? muV : muA;
  int b = blockIdx.x;
  int d = threadIdx.x & 255;
  int part = threadIdx.x >> 8;   // 0..3
  __shared__ float partial[4][256];
  const float* p = X + ((size_t)b*T_ + (size_t)part*(T_/4))*D_ + d;
  float s = 0.f;
  for (int t = 0; t < T_/4; ++t) s += p[(size_t)t * D_];
  partial[part][d] = s;
  __syncthreads();
  if (part == 0)
    mu[b*D_ + d] = (partial[0][d] + partial[1][d] + partial[2][d] + partial[3][d]) * (1.0f/(float)T_);
}

// ---------------- Sigma = Xc^T Xc / (T-1), lower tiles only, +jitter on diag ----------------
__global__ __launch_bounds__(256) void sigma_k(const float* __restrict__ A,
    const float* __restrict__ Vv, const float* __restrict__ muA,
    const float* __restrict__ muV, float* __restrict__ SA, float* __restrict__ SV) {
  const float* X  = blockIdx.z ? Vv  : A;
  const float* mu = blockIdx.z ? muV : muA;
  float* Sg       = blockIdx.z ? SV  : SA;
  const int TIa[10] = {0,1,1,2,2,2,3,3,3,3};
  const int TJa[10] = {0,0,1,0,1,2,0,1,2,3};
  int b = blockIdx.y;
  int I0 = TIa[blockIdx.x]*64, J0 = TJa[blockIdx.x]*64;
  __shared__ float xi[16][64];
  __shared__ float xj[16][64];
  int tid = threadIdx.x;
  int r = tid >> 4, c4 = (tid & 15) * 4;
  float4 mI = *(const float4*)(mu + b*D_ + I0 + c4);
  float4 mJ = *(const float4*)(mu + b*D_ + J0 + c4);
  float acc[4][4] = {};
  int i4 = (tid >> 4) * 4, j4 = (tid & 15) * 4;
  for (int t0 = 0; t0 < T_; t0 += 16) {
    __syncthreads();
    const float* px = X + ((size_t)b*T_ + t0 + r) * D_;
    float4 fa = *(const float4*)(px + I0 + c4);
    xi[r][c4+0] = fa.x - mI.x; xi[r][c4+1] = fa.y - mI.y;
    xi[r][c4+2] = fa.z - mI.z; xi[r][c4+3] = fa.w - mI.w;
    float4 fb = *(const float4*)(px + J0 + c4);
    xj[r][c4+0] = fb.x - mJ.x; xj[r][c4+1] = fb.y - mJ.y;
    xj[r][c4+2] = fb.z - mJ.z; xj[r][c4+3] = fb.w - mJ.w;
    __syncthreads();
    #pragma unroll
    for (int t = 0; t < 16; ++t) {
      float4 qa = *(const float4*)&xi[t][i4];
      float4 qb = *(const float4*)&xj[t][j4];
      acc[0][0] = fmaf(qa.x, qb.x, acc[0][0]); acc[0][1] = fmaf(qa.x, qb.y, acc[0][1]);
      acc[0][2] = fmaf(qa.x, qb.z, acc[0][2]); acc[0][3] = fmaf(qa.x, qb.w, acc[0][3]);
      acc[1][0] = fmaf(qa.y, qb.x, acc[1][0]); acc[1][1] = fmaf(qa.y, qb.y, acc[1][1]);
      acc[1][2] = fmaf(qa.y, qb.z, acc[1][2]); acc[1][3] = fmaf(qa.y, qb.w, acc[1][3]);
      acc[2][0] = fmaf(qa.z, qb.x, acc[2][0]); acc[2][1] = fmaf(qa.z, qb.y, acc[2][1]);
      acc[2][2] = fmaf(qa.z, qb.z, acc[2][2]); acc[2][3] = fmaf(qa.z, qb.w, acc[2][3]);
      acc[3][0] = fmaf(qa.w, qb.x, acc[3][0]); acc[3][1] = fmaf(qa.w, qb.y, acc[3][1]);
      acc[3][2] = fmaf(qa.w, qb.z, acc[3][2]); acc[3][3] = fmaf(qa.w, qb.w, acc[3][3]);
    }
  }
  const float inv = 1.0f / (float)(T_ - 1);
  float* out = Sg + (size_t)b*D_*D_;
  #pragma unroll
  for (int ii = 0; ii < 4; ++ii)
    #pragma unroll
    for (int jj = 0; jj < 4; ++jj) {
      int row = I0 + i4 + ii, col = J0 + j4 + jj;
      float v = acc[ii][jj] * inv;
      if (row == col) v += 1e-6f;
      out[(size_t)row*D_ + col] = v;
    }
}

// ---------------- left-looking Cholesky, one block per (batch, modality) ----------------
__global__ __launch_bounds__(256) void chol_k(float* __restrict__ SA, float* __restrict__ SV) {
  float* M = (blockIdx.y ? SV : SA) + (size_t)blockIdx.x * D_ * D_;
  __shared__ float rowj[256];
  __shared__ float dshare;
  int i = threadIdx.x;
  float* rowi = M + (size_t)i * D_;
  for (int j = 0; j < D_; ++j) {
    __syncthreads();
    if (i < j) rowj[i] = M[(size_t)j*D_ + i];
    __syncthreads();
    float dot = 0.f;
    if (i >= j) {
      float d0 = 0.f, d1 = 0.f, d2 = 0.f, d3 = 0.f;
      int j16 = j & ~15;
      for (int k = 0; k < j16; k += 16) {
        float4 a0 = *(const float4*)(rowi + k);
        float4 a1 = *(const float4*)(rowi + k + 4);
        float4 a2 = *(const float4*)(rowi + k + 8);
        float4 a3 = *(const float4*)(rowi + k + 12);
        d0 += a0.x*rowj[k]    + a0.y*rowj[k+1]  + a0.z*rowj[k+2]  + a0.w*rowj[k+3];
        d1 += a1.x*rowj[k+4]  + a1.y*rowj[k+5]  + a1.z*rowj[k+6]  + a1.w*rowj[k+7];
        d2 += a2.x*rowj[k+8]  + a2.y*rowj[k+9]  + a2.z*rowj[k+10] + a2.w*rowj[k+11];
        d3 += a3.x*rowj[k+12] + a3.y*rowj[k+13] + a3.z*rowj[k+14] + a3.w*rowj[k+15];
      }
      for (int k = j16; k < j; ++k) d0 += rowi[k]*rowj[k];
      dot = (d0 + d1) + (d2 + d3);
    }
    if (i == j) dshare = sqrtf(rowi[j] - dot);
    __syncthreads();
    if (i > j)       rowi[j] = (rowi[j] - dot) / dshare;
    else if (i == j) rowi[j] = dshare;
  }
  __syncthreads();
  for (int k = i + 1; k < D_; ++k) rowi[k] = 0.f;   // zero upper triangle
}

// ---------------- K = mu + eps @ L^T with on-the-fly eps generation ----------------
__global__ __launch_bounds__(256) void kgen_k(const float* __restrict__ L,
    const float* __restrict__ mu, float* __restrict__ Kout, uint32_t key) {
  __shared__ float eps[64][16];
  int b = blockIdx.y;
  int t0 = blockIdx.x * 64;
  int e = threadIdx.x;
  const float* Lr = L + (size_t)b*D_*D_ + (size_t)e*D_;
  float acc[64];
  #pragma unroll
  for (int t = 0; t < 64; ++t) acc[t] = 0.f;
  int gt = threadIdx.x >> 2;
  int gd = (threadIdx.x & 3) * 4;
  for (int d0 = 0; d0 < D_; d0 += 16) {
    __syncthreads();
    uint32_t nbase = ((uint32_t)(b*T_ + t0 + gt)) * (uint32_t)D_ + (uint32_t)(d0 + gd);
    #pragma unroll
    for (int q = 0; q < 4; ++q) eps[gt][gd+q] = jax_normal_elem(key, nbase + q);
    __syncthreads();
    float lreg[16];
    #pragma unroll
    for (int q = 0; q < 16; q += 4) {
      float4 f = *(const float4*)(Lr + d0 + q);
      lreg[q] = f.x; lreg[q+1] = f.y; lreg[q+2] = f.z; lreg[q+3] = f.w;
    }
    #pragma unroll 8
    for (int t = 0; t < 64; ++t) {
      float s = acc[t];
      #pragma unroll
      for (int dd = 0; dd < 16; ++dd) s = fmaf(eps[t][dd], lreg[dd], s);
      acc[t] = s;
    }
  }
  float m = mu[b*D_ + e];
  for (int t = 0; t < 64; ++t)
    Kout[((size_t)b*T_ + t0 + t)*D_ + e] = acc[t] + m;
}

// ---------------- MFMA flash attention: O = softmax(Q K^T / 16) V ----------------
// 64 Q-rows per block, 4 waves; wave w: S-block rows (w>>1)*32, cols (w&1)*32;
//                                 O-strip rows (w>>1)*32, cols (w&1)*128.
#define SCALE_ 0.0625f
#define KSTR 264    // bf16 elems/row: 528 B = rot-4 banking -> conflict-free b128 col reads
#define SFSTR 68    // f32 elems/row
#define PSTR 72     // bf16 elems/row: 144 B = rot-4 banking

__global__ __launch_bounds__(256, 2) void attn_mfma(const float* __restrict__ Qg,
    const float* __restrict__ Kg, const float* __restrict__ Vg,
    float* __restrict__ Og) {
  __shared__ __bf16 KS[64 * KSTR];       // 33792 B
  __shared__ float  Sf[64 * SFSTR];      // 17408 B
  __shared__ __bf16 Ps[64 * PSTR];       //  9216 B
  __shared__ float rowm[64], rowl[64], rowa[64];  // 768 B

  const int tid  = threadIdx.x;
  const int wv   = tid >> 6;
  const int lane = tid & 63;
  const int ln31 = lane & 31;
  const int h8   = (lane >> 5) * 8;     // k-group offset within frag
  const int qb   = (wv >> 1) * 32;      // this wave's Q-row base
  const int sb   = (wv & 1) * 32;       // this wave's S-col (key) base
  const int cb   = (wv & 1) * 128;      // this wave's O-col base
  const int b    = blockIdx.y;
  const int t0   = blockIdx.x * 64;

  // ---- Q into registers as bf16 A-frags (row = qb+ln31, k = dstep*16+h8+j) ----
  bf16x8 qf[16];
  {
    const float* qrow = Qg + ((size_t)b*T_ + t0 + qb + ln31) * D_;
    #pragma unroll
    for (int s = 0; s < 16; ++s) {
      float4 f0 = *(const float4*)(qrow + s*16 + h8);
      float4 f1 = *(const float4*)(qrow + s*16 + h8 + 4);
      bf16x8 q;
      q[0] = (__bf16)f0.x; q[1] = (__bf16)f0.y; q[2] = (__bf16)f0.z; q[3] = (__bf16)f0.w;
      q[4] = (__bf16)f1.x; q[5] = (__bf16)f1.y; q[6] = (__bf16)f1.z; q[7] = (__bf16)f1.w;
      qf[s] = q;
    }
  }
  if (tid < 64) { rowm[tid] = -INFINITY; rowl[tid] = 0.f; }

  float16 oacc[4];
  #pragma unroll
  for (int nb = 0; nb < 4; ++nb)
    #pragma unroll
    for (int i = 0; i < 16; ++i) oacc[nb][i] = 0.f;

  for (int s0 = 0; s0 < T_; s0 += 64) {
    __syncthreads();
    // ---- stage K tile (f32 global, coalesced -> bf16 LDS) ----
    #pragma unroll
    for (int it = 0; it < 16; ++it) {
      int flat = it*1024 + tid*4;
      int r = flat >> 8, c = flat & 255;
      float4 f = *(const float4*)(Kg + ((size_t)b*T_ + s0 + r)*D_ + c);
      bf16x4 u;
      u[0] = (__bf16)f.x; u[1] = (__bf16)f.y; u[2] = (__bf16)f.z; u[3] = (__bf16)f.w;
      *(bf16x4*)&KS[r*KSTR + c] = u;
    }
    __syncthreads();
    // ---- S = Q K^T (one 32x32 block per wave) ----
    float16 sacc = {0.f,0.f,0.f,0.f,0.f,0.f,0.f,0.f,0.f,0.f,0.f,0.f,0.f,0.f,0.f,0.f};
    #pragma unroll
    for (int d = 0; d < 16; ++d) {
      bf16x8 kf = *(const bf16x8*)&KS[(sb + ln31)*KSTR + d*16 + h8];
      sacc = __builtin_amdgcn_mfma_f32_32x32x16_bf16(qf[d], kf, sacc, 0, 0, 0);
    }
    #pragma unroll
    for (int r = 0; r < 16; ++r) {
      int row = qb + (r & 3) + 8*(r >> 2) + 4*(lane >> 5);
      Sf[row*SFSTR + sb + ln31] = sacc[r] * SCALE_;
    }
    __syncthreads();
    // ---- online softmax: 4 threads per row, 16 cols each ----
    {
      int r = tid >> 2, sub = tid & 3;
      const float* srow = &Sf[r*SFSTR + sub*16];
      float4 a0 = *(const float4*)(srow);
      float4 a1 = *(const float4*)(srow + 4);
      float4 a2 = *(const float4*)(srow + 8);
      float4 a3 = *(const float4*)(srow + 12);
      float xv[16] = {a0.x,a0.y,a0.z,a0.w, a1.x,a1.y,a1.z,a1.w,
                      a2.x,a2.y,a2.z,a2.w, a3.x,a3.y,a3.z,a3.w};
      float mloc = xv[0];
      #pragma unroll
      for (int i = 1; i < 16; ++i) mloc = fmaxf(mloc, xv[i]);
      mloc = fmaxf(mloc, __shfl_xor(mloc, 1));
      mloc = fmaxf(mloc, __shfl_xor(mloc, 2));
      float mold = rowm[r];
      float mnew = fmaxf(mold, mloc);
      float ls = 0.f;
      #pragma unroll
      for (int i = 0; i < 16; ++i) { xv[i] = expf(xv[i] - mnew); ls += xv[i]; }
      #pragma unroll
      for (int i = 0; i < 8; ++i) {
        bf16x2 t2; t2[0] = (__bf16)xv[2*i]; t2[1] = (__bf16)xv[2*i+1];
        *(bf16x2*)&Ps[r*PSTR + sub*16 + 2*i] = t2;
      }
      ls += __shfl_xor(ls, 1);
      ls += __shfl_xor(ls, 2);
      if (sub == 0) {
        float al = expf(mold - mnew);
        rowa[r] = al;
        rowl[r] = rowl[r] * al + ls;
        rowm[r] = mnew;
      }
    }
    __syncthreads();
    // ---- rescale O by alpha ----
    #pragma unroll
    for (int r = 0; r < 16; ++r) {
      float al = rowa[qb + (r & 3) + 8*(r >> 2) + 4*(lane >> 5)];
      oacc[0][r] *= al; oacc[1][r] *= al; oacc[2][r] *= al; oacc[3][r] *= al;
    }
    // ---- O += P V  (P from LDS, V frags straight from global/L2) ----
    #pragma unroll
    for (int ks = 0; ks < 4; ++ks) {
      bf16x8 pf = *(const bf16x8*)&Ps[(qb + ln31)*PSTR + ks*16 + h8];
      const float* vbase = Vg + ((size_t)b*T_ + s0 + ks*16 + h8)*D_ + cb + ln31;
      #pragma unroll
      for (int nb = 0; nb < 4; ++nb) {
        const float* vcol = vbase + nb*32;
        bf16x8 vf;
        #pragma unroll
        for (int j = 0; j < 8; ++j) vf[j] = (__bf16)vcol[(size_t)j * D_];
        oacc[nb] = __builtin_amdgcn_mfma_f32_32x32x16_bf16(pf, vf, oacc[nb], 0, 0, 0);
      }
    }
  }
  // ---- epilogue: O /= l, store ----
  #pragma unroll
  for (int r = 0; r < 16; ++r) {
    int row = qb + (r & 3) + 8*(r >> 2) + 4*(lane >> 5);
    float inv = 1.0f / rowl[row];
    float* orow = Og + ((size_t)b*T_ + t0 + row)*D_ + cb + ln31;
    orow[0]  = oacc[0][r] * inv;
    orow[32] = oacc[1][r] * inv;
    orow[64] = oacc[2][r] * inv;
    orow[96] = oacc[3][r] * inv;
  }
}

// ---------------- gates + cosine combine (one wave per (b,t) row) ----------------
__global__ __launch_bounds__(256) void comb_k(const float* __restrict__ A,
    const float* __restrict__ Vv, const float* __restrict__ att1,
    const float* __restrict__ att2, const float* __restrict__ WA,
    const float* __restrict__ WV, const float* __restrict__ bA,
    const float* __restrict__ bV, float* __restrict__ out) {
  int wv = threadIdx.x >> 6;
  int lane = threadIdx.x & 63;
  size_t row = (size_t)blockIdx.x * 4 + wv;
  size_t base = row * D_;
  int d = lane * 4;
  float4 a  = *(const float4*)(A + base + d);
  float4 v  = *(const float4*)(Vv + base + d);
  float4 x  = *(const float4*)(att1 + base + d);
  float4 y  = *(const float4*)(att2 + base + d);
  float4 w1 = *(const float4*)(WA + d);
  float4 w2 = *(const float4*)(WA + 256 + d);
  float4 w3 = *(const float4*)(WV + d);
  float4 w4 = *(const float4*)(WV + 256 + d);
  float sga = a.x*w1.x + a.y*w1.y + a.z*w1.z + a.w*w1.w
            + x.x*w2.x + x.y*w2.y + x.z*w2.z + x.w*w2.w;
  float sgv = v.x*w3.x + v.y*w3.y + v.z*w3.z + v.w*w3.w
            + y.x*w4.x + y.y*w4.y + y.z*w4.z + y.w*w4.w;
  float sav = a.x*v.x + a.y*v.y + a.z*v.z + a.w*v.w;
  float saa = a.x*a.x + a.y*a.y + a.z*a.z + a.w*a.w;
  float svv = v.x*v.x + v.y*v.y + v.z*v.z + v.w*v.w;
  #pragma unroll
  for (int m = 32; m; m >>= 1) {
    sga += __shfl_xor(sga, m);
    sgv += __shfl_xor(sgv, m);
    sav += __shfl_xor(sav, m);
    saa += __shfl_xor(saa, m);
    svv += __shfl_xor(svv, m);
  }
  float gA = 1.0f / (1.0f + expf(-(sga + bA[0])));
  float gV = 1.0f / (1.0f + expf(-(sgv + bV[0])));
  float cs = sav / fmaxf(sqrtf(saa) * sqrtf(svv), 1e-8f);
  float al = 1.0f / (1.0f + expf(-cs));
  float be = 1.0f - al;
  float4 o;
  o.x = al * (gA*a.x + (1.0f-gA)*x.x) + be * (gV*v.x + (1.0f-gV)*y.x);
  o.y = al * (gA*a.y + (1.0f-gA)*x.y) + be * (gV*v.y + (1.0f-gV)*y.y);
  o.z = al * (gA*a.z + (1.0f-gA)*x.z) + be * (gV*v.z + (1.0f-gV)*y.z);
  o.w = al * (gA*a.w + (1.0f-gA)*x.w) + be * (gV*v.w + (1.0f-gV)*y.w);
  *(float4*)(out + base + d) = o;
}

extern "C" void kernel_launch(void* const* d_in, const int* in_sizes, int n_in,
                              void* d_out, int out_size, void* d_ws, size_t ws_size,
                              hipStream_t stream) {
  (void)in_sizes; (void)n_in; (void)out_size; (void)ws_size;
  const float* A  = (const float*)d_in[0];
  const float* V  = (const float*)d_in[1];
  const float* WA = (const float*)d_in[2];
  const float* WV = (const float*)d_in[3];
  const float* bA = (const float*)d_in[4];
  const float* bV = (const float*)d_in[5];
  float* ws  = (float*)d_ws;
  float* muA = ws;                                  // 4096
  float* muV = muA + 4096;                          // 4096
  float* LA  = muV + 4096;                          // 16*256*256
  float* LV  = LA + (size_t)B_*D_*D_;               // 16*256*256
  float* Kb  = LV + (size_t)B_*D_*D_;               // N_ (K_v then reused for K_a)
  float* at1 = Kb + (size_t)N_;                     // N_ att_av
  float* at2 = at1 + (size_t)N_;                    // N_ att_va
  // total ws: 27,271,168 floats = ~104 MB

  mean_k<<<dim3(16,2), dim3(1024), 0, stream>>>(A, V, muA, muV);
  sigma_k<<<dim3(10,16,2), dim3(256), 0, stream>>>(A, V, muA, muV, LA, LV);
  chol_k<<<dim3(16,2), dim3(256), 0, stream>>>(LA, LV);
  // K_v = resample(V, key 42): audio queries attend to it, values = V
  kgen_k<<<dim3(32,16), dim3(256), 0, stream>>>(LV, muV, Kb, 42u);
  attn_mfma<<<dim3(32,16), dim3(256), 0, stream>>>(A, Kb, V, at1);
  // K_a = resample(A, key 43): visual queries attend to it, values = A
  kgen_k<<<dim3(32,16), dim3(256), 0, stream>>>(LA, muA, Kb, 43u);
  attn_mfma<<<dim3(32,16), dim3(256), 0, stream>>>(V, Kb, A, at2);
  comb_k<<<dim3(8192), dim3(256), 0, stream>>>(A, V, at1, at2, WA, WV, bA, bV, (float*)d_out);
}

// Round 3
// 1406.874 us; speedup vs baseline: 3.0451x; 1.4192x over previous
//
#include <hip/hip_runtime.h>
#include <stdint.h>
#include <math.h>

#define B_ 16
#define T_ 2048
#define D_ 256
#define N_ (B_*T_*D_)   // 8388608

typedef __attribute__((ext_vector_type(8)))  __bf16 bf16x8;
typedef __attribute__((ext_vector_type(4)))  __bf16 bf16x4;
typedef __attribute__((ext_vector_type(2)))  __bf16 bf16x2;
typedef __attribute__((ext_vector_type(16))) float  float16;

// ---------------- JAX threefry2x32 (partitionable layout) ----------------
__device__ __forceinline__ uint32_t rotl32(uint32_t v, int r) {
  return (v << r) | (v >> (32 - r));
}

__device__ __forceinline__ void threefry2x32(uint32_t k0, uint32_t k1,
                                             uint32_t x0, uint32_t x1,
                                             uint32_t& o0, uint32_t& o1) {
  uint32_t ks2 = k0 ^ k1 ^ 0x1BD11BDAu;
#define TF_ROUND(r) { x0 += x1; x1 = rotl32(x1, r); x1 ^= x0; }
  x0 += k0; x1 += k1;
  TF_ROUND(13) TF_ROUND(15) TF_ROUND(26) TF_ROUND(6)
  x0 += k1; x1 += ks2 + 1u;
  TF_ROUND(17) TF_ROUND(29) TF_ROUND(16) TF_ROUND(24)
  x0 += ks2; x1 += k0 + 2u;
  TF_ROUND(13) TF_ROUND(15) TF_ROUND(26) TF_ROUND(6)
  x0 += k0; x1 += k1 + 3u;
  TF_ROUND(17) TF_ROUND(29) TF_ROUND(16) TF_ROUND(24)
  x0 += k1; x1 += ks2 + 4u;
  TF_ROUND(13) TF_ROUND(15) TF_ROUND(26) TF_ROUND(6)
  x0 += ks2; x1 += k0 + 5u;
#undef TF_ROUND
  o0 = x0; o1 = x1;
}

// XLA ErfInv f32 polynomial (Giles)
__device__ __forceinline__ float erfinv_xla(float x) {
  float w = -log1pf(-x * x);
  float p;
  if (w < 5.0f) {
    w -= 2.5f;
    p = 2.81022636e-08f;
    p = fmaf(p, w, 3.43273939e-07f);
    p = fmaf(p, w, -3.5233877e-06f);
    p = fmaf(p, w, -4.39150654e-06f);
    p = fmaf(p, w, 0.00021858087f);
    p = fmaf(p, w, -0.00125372503f);
    p = fmaf(p, w, -0.00417768164f);
    p = fmaf(p, w, 0.246640727f);
    p = fmaf(p, w, 1.50140941f);
  } else {
    w = sqrtf(w) - 3.0f;
    p = -0.000200214257f;
    p = fmaf(p, w, 0.000100950558f);
    p = fmaf(p, w, 0.00134934322f);
    p = fmaf(p, w, -0.00367342844f);
    p = fmaf(p, w, 0.00573950773f);
    p = fmaf(p, w, -0.0076224613f);
    p = fmaf(p, w, 0.00943887047f);
    p = fmaf(p, w, 1.00167406f);
    p = fmaf(p, w, 2.83297682f);
  }
  return p * x;
}

// jax.random.normal element n (flat row-major index), key=(0, seed)
__device__ __forceinline__ float jax_normal_elem(uint32_t key, uint32_t n) {
  uint32_t o0, o1;
  threefry2x32(0u, key, 0u, n, o0, o1);
  uint32_t bits = o0 ^ o1;                     // partitionable 32-bit output
  float f = __uint_as_float((bits >> 9) | 0x3f800000u) - 1.0f;  // [0,1)
  const float lo = -0.99999994f;               // nextafter(-1,0)
  float u = fmaxf(lo, fmaf(f, 2.0f, lo));      // (maxval-minval) rounds to 2.0f
  return 1.41421356f * erfinv_xla(u);          // sqrt(2) in f32
}

// ---------------- mean over T ----------------
__global__ __launch_bounds__(1024) void mean_k(const float* __restrict__ A,
    const float* __restrict__ Vv, float* __restrict__ muA, float* __restrict__ muV) {
  const float* X = blockIdx.y ? Vv : A;
  float* mu = blockIdx.y ? muV : muA;
  int b = blockIdx.x;
  int d = threadIdx.x & 255;
  int part = threadIdx.x >> 8;   // 0..3
  __shared__ float partial[4][256];
  const float* p = X + ((size_t)b*T_ + (size_t)part*(T_/4))*D_ + d;
  float s = 0.f;
  for (int t = 0; t < T_/4; ++t) s += p[(size_t)t * D_];
  partial[part][d] = s;
  __syncthreads();
  if (part == 0)
    mu[b*D_ + d] = (partial[0][d] + partial[1][d] + partial[2][d] + partial[3][d]) * (1.0f/(float)T_);
}

// ---------------- Sigma = Xc^T Xc / (T-1), lower tiles only, +jitter on diag ----------------
__global__ __launch_bounds__(256) void sigma_k(const float* __restrict__ A,
    const float* __restrict__ Vv, const float* __restrict__ muA,
    const float* __restrict__ muV, float* __restrict__ SA, float* __restrict__ SV) {
  const float* X  = blockIdx.z ? Vv  : A;
  const float* mu = blockIdx.z ? muV : muA;
  float* Sg       = blockIdx.z ? SV  : SA;
  const int TIa[10] = {0,1,1,2,2,2,3,3,3,3};
  const int TJa[10] = {0,0,1,0,1,2,0,1,2,3};
  int b = blockIdx.y;
  int I0 = TIa[blockIdx.x]*64, J0 = TJa[blockIdx.x]*64;
  __shared__ float xi[16][64];
  __shared__ float xj[16][64];
  int tid = threadIdx.x;
  int r = tid >> 4, c4 = (tid & 15) * 4;
  float4 mI = *(const float4*)(mu + b*D_ + I0 + c4);
  float4 mJ = *(const float4*)(mu + b*D_ + J0 + c4);
  float acc[4][4] = {};
  int i4 = (tid >> 4) * 4, j4 = (tid & 15) * 4;
  for (int t0 = 0; t0 < T_; t0 += 16) {
    __syncthreads();
    const float* px = X + ((size_t)b*T_ + t0 + r) * D_;
    float4 fa = *(const float4*)(px + I0 + c4);
    xi[r][c4+0] = fa.x - mI.x; xi[r][c4+1] = fa.y - mI.y;
    xi[r][c4+2] = fa.z - mI.z; xi[r][c4+3] = fa.w - mI.w;
    float4 fb = *(const float4*)(px + J0 + c4);
    xj[r][c4+0] = fb.x - mJ.x; xj[r][c4+1] = fb.y - mJ.y;
    xj[r][c4+2] = fb.z - mJ.z; xj[r][c4+3] = fb.w - mJ.w;
    __syncthreads();
    #pragma unroll
    for (int t = 0; t < 16; ++t) {
      float4 qa = *(const float4*)&xi[t][i4];
      float4 qb = *(const float4*)&xj[t][j4];
      acc[0][0] = fmaf(qa.x, qb.x, acc[0][0]); acc[0][1] = fmaf(qa.x, qb.y, acc[0][1]);
      acc[0][2] = fmaf(qa.x, qb.z, acc[0][2]); acc[0][3] = fmaf(qa.x, qb.w, acc[0][3]);
      acc[1][0] = fmaf(qa.y, qb.x, acc[1][0]); acc[1][1] = fmaf(qa.y, qb.y, acc[1][1]);
      acc[1][2] = fmaf(qa.y, qb.z, acc[1][2]); acc[1][3] = fmaf(qa.y, qb.w, acc[1][3]);
      acc[2][0] = fmaf(qa.z, qb.x, acc[2][0]); acc[2][1] = fmaf(qa.z, qb.y, acc[2][1]);
      acc[2][2] = fmaf(qa.z, qb.z, acc[2][2]); acc[2][3] = fmaf(qa.z, qb.w, acc[2][3]);
      acc[3][0] = fmaf(qa.w, qb.x, acc[3][0]); acc[3][1] = fmaf(qa.w, qb.y, acc[3][1]);
      acc[3][2] = fmaf(qa.w, qb.z, acc[3][2]); acc[3][3] = fmaf(qa.w, qb.w, acc[3][3]);
    }
  }
  const float inv = 1.0f / (float)(T_ - 1);
  float* out = Sg + (size_t)b*D_*D_;
  #pragma unroll
  for (int ii = 0; ii < 4; ++ii)
    #pragma unroll
    for (int jj = 0; jj < 4; ++jj) {
      int row = I0 + i4 + ii, col = J0 + j4 + jj;
      float v = acc[ii][jj] * inv;
      if (row == col) v += 1e-6f;
      out[(size_t)row*D_ + col] = v;
    }
}

// ---------------- blocked left-looking Cholesky, one block per (batch, modality) ----------------
// Panel NB=32: GEMM update (LDS-staged diag rows, per-thread row in L1) then
// 32-step micro-factor with the panel row held in VGPRs and diag block in LDS.
#define CNB 32

__global__ __launch_bounds__(256) void chol_k(float* __restrict__ SA, float* __restrict__ SV) {
  float* M = (blockIdx.y ? SV : SA) + (size_t)blockIdx.x * D_ * D_;
  __shared__ float SB[CNB][16];       // staged diag-block rows over k-chunk  (2 KB)
  __shared__ float PL[CNB][36];       // finalized diag block, stride 36 (16B-aligned rows)
  __shared__ float dval_sh, dinv_sh;

  const int i = threadIdx.x;          // row owned by this thread
  float* rowi = M + (size_t)i * D_;

  for (int J = 0; J < D_; J += CNB) {
    const bool active = (i >= J);
    // acc[jj] = A[i, J+jj]
    float acc[CNB];
    if (active) {
      #pragma unroll
      for (int q = 0; q < CNB; q += 4) {
        float4 f = *(const float4*)(rowi + J + q);
        acc[q] = f.x; acc[q+1] = f.y; acc[q+2] = f.z; acc[q+3] = f.w;
      }
    } else {
      #pragma unroll
      for (int q = 0; q < CNB; ++q) acc[q] = 0.f;
    }
    // zero PL (upper part must stay 0 so micro-dot needs no predication)
    for (int t = i; t < CNB*36; t += 256) ((float*)PL)[t] = 0.f;

    // ---- GEMM update: acc[jj] -= sum_{k<J} L[i,k] * L[J+jj,k] ----
    for (int k0 = 0; k0 < J; k0 += 16) {
      __syncthreads();
      {  // stage SB[jj][c] = L[J+jj, k0+c]; 512 elems, 2 per thread
        int jj = i >> 3, c = (i & 7) * 2;
        float2 f = *(const float2*)(M + (size_t)(J + jj) * D_ + k0 + c);
        SB[jj][c] = f.x; SB[jj][c+1] = f.y;
      }
      __syncthreads();
      if (active) {
        float lv[16];
        #pragma unroll
        for (int q = 0; q < 16; q += 4) {
          float4 f = *(const float4*)(rowi + k0 + q);
          lv[q] = f.x; lv[q+1] = f.y; lv[q+2] = f.z; lv[q+3] = f.w;
        }
        #pragma unroll
        for (int jj = 0; jj < CNB; ++jj) {
          float s = 0.f;
          #pragma unroll
          for (int c = 0; c < 16; c += 4) {
            float4 b4 = *(const float4*)&SB[jj][c];
            s = fmaf(lv[c],   b4.x, s); s = fmaf(lv[c+1], b4.y, s);
            s = fmaf(lv[c+2], b4.z, s); s = fmaf(lv[c+3], b4.w, s);
          }
          acc[jj] -= s;
        }
      }
    }
    __syncthreads();

    // ---- micro-factor the 32-wide panel ----
    float lrow[CNB];
    #pragma unroll
    for (int q = 0; q < CNB; ++q) lrow[q] = 0.f;
    for (int jj = 0; jj < CNB; ++jj) {
      const int j = J + jj;
      float val = 0.f;
      if (i >= j) {
        float s = 0.f;
        #pragma unroll
        for (int kq = 0; kq < CNB; kq += 4) {
          float4 p4 = *(const float4*)&PL[jj][kq];
          s = fmaf(lrow[kq],   p4.x, s); s = fmaf(lrow[kq+1], p4.y, s);
          s = fmaf(lrow[kq+2], p4.z, s); s = fmaf(lrow[kq+3], p4.w, s);
        }
        val = acc[jj] - s;
      }
      if (i == j) { float d = sqrtf(val); dval_sh = d; dinv_sh = 1.0f / d; }
      __syncthreads();
      if (i >= j) {
        float lv = (i == j) ? dval_sh : val * dinv_sh;
        lrow[jj] = lv;
        if (i < J + CNB) PL[i - J][jj] = lv;
      }
      __syncthreads();
    }
    // ---- write panel back (upper-within-panel rows i>=J get zeros beyond col i) ----
    if (active) {
      #pragma unroll
      for (int q = 0; q < CNB; q += 4)
        *(float4*)(rowi + J + q) = make_float4(lrow[q], lrow[q+1], lrow[q+2], lrow[q+3]);
    }
    __syncthreads();
  }
  // zero remaining upper triangle (cols beyond this row's panel band)
  for (int k = i + 1; k < D_; ++k) rowi[k] = 0.f;
}

// ---------------- K = mu + eps @ L^T with on-the-fly eps generation ----------------
__global__ __launch_bounds__(256) void kgen_k(const float* __restrict__ L,
    const float* __restrict__ mu, float* __restrict__ Kout, uint32_t key) {
  __shared__ float eps[64][16];
  int b = blockIdx.y;
  int t0 = blockIdx.x * 64;
  int e = threadIdx.x;
  const float* Lr = L + (size_t)b*D_*D_ + (size_t)e*D_;
  float acc[64];
  #pragma unroll
  for (int t = 0; t < 64; ++t) acc[t] = 0.f;
  int gt = threadIdx.x >> 2;
  int gd = (threadIdx.x & 3) * 4;
  for (int d0 = 0; d0 < D_; d0 += 16) {
    __syncthreads();
    uint32_t nbase = ((uint32_t)(b*T_ + t0 + gt)) * (uint32_t)D_ + (uint32_t)(d0 + gd);
    #pragma unroll
    for (int q = 0; q < 4; ++q) eps[gt][gd+q] = jax_normal_elem(key, nbase + q);
    __syncthreads();
    float lreg[16];
    #pragma unroll
    for (int q = 0; q < 16; q += 4) {
      float4 f = *(const float4*)(Lr + d0 + q);
      lreg[q] = f.x; lreg[q+1] = f.y; lreg[q+2] = f.z; lreg[q+3] = f.w;
    }
    #pragma unroll 8
    for (int t = 0; t < 64; ++t) {
      float s = acc[t];
      #pragma unroll
      for (int dd = 0; dd < 16; ++dd) s = fmaf(eps[t][dd], lreg[dd], s);
      acc[t] = s;
    }
  }
  float m = mu[b*D_ + e];
  for (int t = 0; t < 64; ++t)
    Kout[((size_t)b*T_ + t0 + t)*D_ + e] = acc[t] + m;
}

// ---------------- MFMA flash attention: O = softmax(Q K^T / 16) V ----------------
// 64 Q-rows per block, 4 waves; wave w: S-block rows (w>>1)*32, cols (w&1)*32;
//                                 O-strip rows (w>>1)*32, cols (w&1)*128.
#define SCALE_ 0.0625f
#define KSTR 264    // bf16 elems/row: 528 B = rot-4 banking -> conflict-free b128 col reads
#define SFSTR 68    // f32 elems/row
#define PSTR 72     // bf16 elems/row: 144 B = rot-4 banking

__global__ __launch_bounds__(256, 2) void attn_mfma(const float* __restrict__ Qg,
    const float* __restrict__ Kg, const float* __restrict__ Vg,
    float* __restrict__ Og) {
  __shared__ __bf16 KS[64 * KSTR];       // 33792 B
  __shared__ float  Sf[64 * SFSTR];      // 17408 B
  __shared__ __bf16 Ps[64 * PSTR];       //  9216 B
  __shared__ float rowm[64], rowl[64], rowa[64];  // 768 B

  const int tid  = threadIdx.x;
  const int wv   = tid >> 6;
  const int lane = tid & 63;
  const int ln31 = lane & 31;
  const int h8   = (lane >> 5) * 8;     // k-group offset within frag
  const int qb   = (wv >> 1) * 32;      // this wave's Q-row base
  const int sb   = (wv & 1) * 32;       // this wave's S-col (key) base
  const int cb   = (wv & 1) * 128;      // this wave's O-col base
  const int b    = blockIdx.y;
  const int t0   = blockIdx.x * 64;

  // ---- Q into registers as bf16 A-frags (row = qb+ln31, k = dstep*16+h8+j) ----
  bf16x8 qf[16];
  {
    const float* qrow = Qg + ((size_t)b*T_ + t0 + qb + ln31) * D_;
    #pragma unroll
    for (int s = 0; s < 16; ++s) {
      float4 f0 = *(const float4*)(qrow + s*16 + h8);
      float4 f1 = *(const float4*)(qrow + s*16 + h8 + 4);
      bf16x8 q;
      q[0] = (__bf16)f0.x; q[1] = (__bf16)f0.y; q[2] = (__bf16)f0.z; q[3] = (__bf16)f0.w;
      q[4] = (__bf16)f1.x; q[5] = (__bf16)f1.y; q[6] = (__bf16)f1.z; q[7] = (__bf16)f1.w;
      qf[s] = q;
    }
  }
  if (tid < 64) { rowm[tid] = -INFINITY; rowl[tid] = 0.f; }

  float16 oacc[4];
  #pragma unroll
  for (int nb = 0; nb < 4; ++nb)
    #pragma unroll
    for (int i = 0; i < 16; ++i) oacc[nb][i] = 0.f;

  for (int s0 = 0; s0 < T_; s0 += 64) {
    __syncthreads();
    // ---- stage K tile (f32 global, coalesced -> bf16 LDS) ----
    #pragma unroll
    for (int it = 0; it < 16; ++it) {
      int flat = it*1024 + tid*4;
      int r = flat >> 8, c = flat & 255;
      float4 f = *(const float4*)(Kg + ((size_t)b*T_ + s0 + r)*D_ + c);
      bf16x4 u;
      u[0] = (__bf16)f.x; u[1] = (__bf16)f.y; u[2] = (__bf16)f.z; u[3] = (__bf16)f.w;
      *(bf16x4*)&KS[r*KSTR + c] = u;
    }
    __syncthreads();
    // ---- S = Q K^T (one 32x32 block per wave) ----
    float16 sacc = {0.f,0.f,0.f,0.f,0.f,0.f,0.f,0.f,0.f,0.f,0.f,0.f,0.f,0.f,0.f,0.f};
    #pragma unroll
    for (int d = 0; d < 16; ++d) {
      bf16x8 kf = *(const bf16x8*)&KS[(sb + ln31)*KSTR + d*16 + h8];
      sacc = __builtin_amdgcn_mfma_f32_32x32x16_bf16(qf[d], kf, sacc, 0, 0, 0);
    }
    #pragma unroll
    for (int r = 0; r < 16; ++r) {
      int row = qb + (r & 3) + 8*(r >> 2) + 4*(lane >> 5);
      Sf[row*SFSTR + sb + ln31] = sacc[r] * SCALE_;
    }
    __syncthreads();
    // ---- online softmax: 4 threads per row, 16 cols each ----
    {
      int r = tid >> 2, sub = tid & 3;
      const float* srow = &Sf[r*SFSTR + sub*16];
      float4 a0 = *(const float4*)(srow);
      float4 a1 = *(const float4*)(srow + 4);
      float4 a2 = *(const float4*)(srow + 8);
      float4 a3 = *(const float4*)(srow + 12);
      float xv[16] = {a0.x,a0.y,a0.z,a0.w, a1.x,a1.y,a1.z,a1.w,
                      a2.x,a2.y,a2.z,a2.w, a3.x,a3.y,a3.z,a3.w};
      float mloc = xv[0];
      #pragma unroll
      for (int i = 1; i < 16; ++i) mloc = fmaxf(mloc, xv[i]);
      mloc = fmaxf(mloc, __shfl_xor(mloc, 1));
      mloc = fmaxf(mloc, __shfl_xor(mloc, 2));
      float mold = rowm[r];
      float mnew = fmaxf(mold, mloc);
      float ls = 0.f;
      #pragma unroll
      for (int i = 0; i < 16; ++i) { xv[i] = expf(xv[i] - mnew); ls += xv[i]; }
      #pragma unroll
      for (int i = 0; i < 8; ++i) {
        bf16x2 t2; t2[0] = (__bf16)xv[2*i]; t2[1] = (__bf16)xv[2*i+1];
        *(bf16x2*)&Ps[r*PSTR + sub*16 + 2*i] = t2;
      }
      ls += __shfl_xor(ls, 1);
      ls += __shfl_xor(ls, 2);
      if (sub == 0) {
        float al = expf(mold - mnew);
        rowa[r] = al;
        rowl[r] = rowl[r] * al + ls;
        rowm[r] = mnew;
      }
    }
    __syncthreads();
    // ---- rescale O by alpha ----
    #pragma unroll
    for (int r = 0; r < 16; ++r) {
      float al = rowa[qb + (r & 3) + 8*(r >> 2) + 4*(lane >> 5)];
      oacc[0][r] *= al; oacc[1][r] *= al; oacc[2][r] *= al; oacc[3][r] *= al;
    }
    // ---- O += P V  (P from LDS, V frags straight from global/L2) ----
    #pragma unroll
    for (int ks = 0; ks < 4; ++ks) {
      bf16x8 pf = *(const bf16x8*)&Ps[(qb + ln31)*PSTR + ks*16 + h8];
      const float* vbase = Vg + ((size_t)b*T_ + s0 + ks*16 + h8)*D_ + cb + ln31;
      #pragma unroll
      for (int nb = 0; nb < 4; ++nb) {
        const float* vcol = vbase + nb*32;
        bf16x8 vf;
        #pragma unroll
        for (int j = 0; j < 8; ++j) vf[j] = (__bf16)vcol[(size_t)j * D_];
        oacc[nb] = __builtin_amdgcn_mfma_f32_32x32x16_bf16(pf, vf, oacc[nb], 0, 0, 0);
      }
    }
  }
  // ---- epilogue: O /= l, store ----
  #pragma unroll
  for (int r = 0; r < 16; ++r) {
    int row = qb + (r & 3) + 8*(r >> 2) + 4*(lane >> 5);
    float inv = 1.0f / rowl[row];
    float* orow = Og + ((size_t)b*T_ + t0 + row)*D_ + cb + ln31;
    orow[0]  = oacc[0][r] * inv;
    orow[32] = oacc[1][r] * inv;
    orow[64] = oacc[2][r] * inv;
    orow[96] = oacc[3][r] * inv;
  }
}

// ---------------- gates + cosine combine (one wave per (b,t) row) ----------------
__global__ __launch_bounds__(256) void comb_k(const float* __restrict__ A,
    const float* __restrict__ Vv, const float* __restrict__ att1,
    const float* __restrict__ att2, const float* __restrict__ WA,
    const float* __restrict__ WV, const float* __restrict__ bA,
    const float* __restrict__ bV, float* __restrict__ out) {
  int wv = threadIdx.x >> 6;
  int lane = threadIdx.x & 63;
  size_t row = (size_t)blockIdx.x * 4 + wv;
  size_t base = row * D_;
  int d = lane * 4;
  float4 a  = *(const float4*)(A + base + d);
  float4 v  = *(const float4*)(Vv + base + d);
  float4 x  = *(const float4*)(att1 + base + d);
  float4 y  = *(const float4*)(att2 + base + d);
  float4 w1 = *(const float4*)(WA + d);
  float4 w2 = *(const float4*)(WA + 256 + d);
  float4 w3 = *(const float4*)(WV + d);
  float4 w4 = *(const float4*)(WV + 256 + d);
  float sga = a.x*w1.x + a.y*w1.y + a.z*w1.z + a.w*w1.w
            + x.x*w2.x + x.y*w2.y + x.z*w2.z + x.w*w2.w;
  float sgv = v.x*w3.x + v.y*w3.y + v.z*w3.z + v.w*w3.w
            + y.x*w4.x + y.y*w4.y + y.z*w4.z + y.w*w4.w;
  float sav = a.x*v.x + a.y*v.y + a.z*v.z + a.w*v.w;
  float saa = a.x*a.x + a.y*a.y + a.z*a.z + a.w*a.w;
  float svv = v.x*v.x + v.y*v.y + v.z*v.z + v.w*v.w;
  #pragma unroll
  for (int m = 32; m; m >>= 1) {
    sga += __shfl_xor(sga, m);
    sgv += __shfl_xor(sgv, m);
    sav += __shfl_xor(sav, m);
    saa += __shfl_xor(saa, m);
    svv += __shfl_xor(svv, m);
  }
  float gA = 1.0f / (1.0f + expf(-(sga + bA[0])));
  float gV = 1.0f / (1.0f + expf(-(sgv + bV[0])));
  float cs = sav / fmaxf(sqrtf(saa) * sqrtf(svv), 1e-8f);
  float al = 1.0f / (1.0f + expf(-cs));
  float be = 1.0f - al;
  float4 o;
  o.x = al * (gA*a.x + (1.0f-gA)*x.x) + be * (gV*v.x + (1.0f-gV)*y.x);
  o.y = al * (gA*a.y + (1.0f-gA)*x.y) + be * (gV*v.y + (1.0f-gV)*y.y);
  o.z = al * (gA*a.z + (1.0f-gA)*x.z) + be * (gV*v.z + (1.0f-gV)*y.z);
  o.w = al * (gA*a.w + (1.0f-gA)*x.w) + be * (gV*v.w + (1.0f-gV)*y.w);
  *(float4*)(out + base + d) = o;
}

extern "C" void kernel_launch(void* const* d_in, const int* in_sizes, int n_in,
                              void* d_out, int out_size, void* d_ws, size_t ws_size,
                              hipStream_t stream) {
  (void)in_sizes; (void)n_in; (void)out_size; (void)ws_size;
  const float* A  = (const float*)d_in[0];
  const float* V  = (const float*)d_in[1];
  const float* WA = (const float*)d_in[2];
  const float* WV = (const float*)d_in[3];
  const float* bA = (const float*)d_in[4];
  const float* bV = (const float*)d_in[5];
  float* ws  = (float*)d_ws;
  float* muA = ws;                                  // 4096
  float* muV = muA + 4096;                          // 4096
  float* LA  = muV + 4096;                          // 16*256*256
  float* LV  = LA + (size_t)B_*D_*D_;               // 16*256*256
  float* Kb  = LV + (size_t)B_*D_*D_;               // N_ (K_v then reused for K_a)
  float* at1 = Kb + (size_t)N_;                     // N_ att_av
  float* at2 = at1 + (size_t)N_;                    // N_ att_va
  // total ws: 27,271,168 floats = ~104 MB

  mean_k<<<dim3(16,2), dim3(1024), 0, stream>>>(A, V, muA, muV);
  sigma_k<<<dim3(10,16,2), dim3(256), 0, stream>>>(A, V, muA, muV, LA, LV);
  chol_k<<<dim3(16,2), dim3(256), 0, stream>>>(LA, LV);
  // K_v = resample(V, key 42): audio queries attend to it, values = V
  kgen_k<<<dim3(32,16), dim3(256), 0, stream>>>(LV, muV, Kb, 42u);
  attn_mfma<<<dim3(32,16), dim3(256), 0, stream>>>(A, Kb, V, at1);
  // K_a = resample(A, key 43): visual queries attend to it, values = A
  kgen_k<<<dim3(32,16), dim3(256), 0, stream>>>(LA, muA, Kb, 43u);
  attn_mfma<<<dim3(32,16), dim3(256), 0, stream>>>(V, Kb, A, at2);
  comb_k<<<dim3(8192), dim3(256), 0, stream>>>(A, V, at1, at2, WA, WV, bA, bV, (float*)d_out);
}